// Round 1
// baseline (623.432 us; speedup 1.0000x reference)
//
#include <hip/hip_runtime.h>
#include <math.h>

#define S64 64
#define CH 256
#define NLOC (8 * 64 * 64)   // 32768 locations

// ---------------------------------------------------------------------------
// K1: v = x @ Wv + bv    (x:[32768,256], Wv:[256,256])
// 8 locations per block, 256 threads (thread = output channel).
__global__ __launch_bounds__(256) void k_gemm_v(
    const float* __restrict__ x, const float* __restrict__ Wv,
    const float* __restrict__ bv, float* __restrict__ v) {
  __shared__ float xs[8 * 256];
  const int tid = threadIdx.x;
  const int loc0 = blockIdx.x * 8;
  const float* xb = x + (size_t)loc0 * CH;
  for (int i = tid; i < 8 * 256; i += 256) xs[i] = xb[i];
  __syncthreads();
  float acc[8] = {0.f, 0.f, 0.f, 0.f, 0.f, 0.f, 0.f, 0.f};
  for (int k = 0; k < 256; ++k) {
    float wv = Wv[k * 256 + tid];
#pragma unroll
    for (int t = 0; t < 8; ++t) acc[t] = fmaf(xs[t * 256 + k], wv, acc[t]);
  }
  const float bb = bv[tid];
#pragma unroll
  for (int t = 0; t < 8; ++t) v[(size_t)(loc0 + t) * CH + tid] = acc[t] + bb;
}

// ---------------------------------------------------------------------------
// K2: A = softmax9(x @ Wa + ba)   (Wa:[256,81]; softmax over groups of 9)
// 16 locations per block.
__global__ __launch_bounds__(256) void k_gemm_a(
    const float* __restrict__ x, const float* __restrict__ Wa,
    const float* __restrict__ ba, float* __restrict__ A) {
  __shared__ float xs[16 * 256];
  __shared__ float lg[16 * 81];
  const int tid = threadIdx.x;
  const int loc0 = blockIdx.x * 16;
  const float* xb = x + (size_t)loc0 * CH;
  for (int i = tid; i < 16 * 256; i += 256) xs[i] = xb[i];
  __syncthreads();
  for (int idx = tid; idx < 16 * 81; idx += 256) {
    int t = idx / 81, o = idx % 81;
    float acc = ba[o];
    const float* xr = &xs[t * 256];
    for (int k = 0; k < 256; ++k) acc = fmaf(xr[k], Wa[k * 81 + o], acc);
    lg[idx] = acc;
  }
  __syncthreads();
  for (int row = tid; row < 16 * 9; row += 256) {
    int t = row / 9, p = row % 9;
    float* r = &lg[t * 81 + p * 9];
    float vals[9];
#pragma unroll
    for (int q = 0; q < 9; ++q) vals[q] = r[q];
    float m = vals[0];
#pragma unroll
    for (int q = 1; q < 9; ++q) m = fmaxf(m, vals[q]);
    float ssum = 0.f;
#pragma unroll
    for (int q = 0; q < 9; ++q) { vals[q] = expf(vals[q] - m); ssum += vals[q]; }
    float inv = 1.f / ssum;
    float* o = &A[(size_t)(loc0 + t) * 81 + p * 9];
#pragma unroll
    for (int q = 0; q < 9; ++q) o[q] = vals[q] * inv;
  }
}

// ---------------------------------------------------------------------------
// K3: fused attention-gather (unfold/einsum/fold collapsed to 5x5 gather of v
//     with combined weights) + maxpool3 + relus -> x1[b,alpha,beta,c]
// One block per output location.
__global__ __launch_bounds__(256) void k_attn(
    const float* __restrict__ A, const float* __restrict__ v,
    const float* __restrict__ x, float* __restrict__ x1) {
  __shared__ float a81[81];
  __shared__ float w5[25];
  const int tid = threadIdx.x;
  const int blk = blockIdx.x;
  const int beta = blk & 63;
  const int alpha = (blk >> 6) & 63;
  const int b = blk >> 12;
  if (tid < 81) {
    int ij = tid / 9;          // i*3 + j
    int i = ij / 3, j = ij % 3;
    int lh = beta + 1 - i;     // neighbor location in a-grid (h-major)
    int lw = alpha + 1 - j;
    float val = 0.f;
    if ((unsigned)lh < 64u && (unsigned)lw < 64u)
      val = A[(size_t)(b * 4096 + lh * 64 + lw) * 81 + tid];
    a81[tid] = val;
  }
  __syncthreads();
  if (tid < 25) {
    int dh = tid / 5 - 2, dw = tid % 5 - 2;
    float s = 0.f;
    int jlo = dh < 0 ? -dh : 0, jhi = dh > 0 ? 2 - dh : 2;
    int ilo = dw < 0 ? -dw : 0, ihi = dw > 0 ? 2 - dw : 2;
    for (int j = jlo; j <= jhi; ++j)
      for (int i = ilo; i <= ihi; ++i) {
        int jp = j + dh, ip = i + dw;
        s += a81[(i * 3 + j) * 9 + (ip * 3 + jp)];
      }
    w5[tid] = s;
  }
  __syncthreads();
  // gather v over 5x5 neighborhood: v[b, alpha+dh, beta+dw, c]
  float acc = 0.f;
  const float* vb = v + (size_t)b * 4096 * CH;
#pragma unroll
  for (int dh = -2; dh <= 2; ++dh) {
    int hv = alpha + dh;
    if ((unsigned)hv >= 64u) continue;
#pragma unroll
    for (int dw = -2; dw <= 2; ++dw) {
      int wv = beta + dw;
      if ((unsigned)wv >= 64u) continue;
      float wgt = w5[(dh + 2) * 5 + (dw + 2)];
      acc = fmaf(wgt, vb[(size_t)(hv * 64 + wv) * CH + tid], acc);
    }
  }
  // maxpool3 of x at (alpha, beta)
  const float* xb = x + (size_t)b * 4096 * CH;
  float m1 = -INFINITY;
#pragma unroll
  for (int dh = -1; dh <= 1; ++dh) {
    int hh = alpha + dh;
    if ((unsigned)hh >= 64u) continue;
#pragma unroll
    for (int dw = -1; dw <= 1; ++dw) {
      int ww = beta + dw;
      if ((unsigned)ww >= 64u) continue;
      m1 = fmaxf(m1, xb[(size_t)(hh * 64 + ww) * CH + tid]);
    }
  }
  float xr = fmaxf(acc, 0.f);
  x1[(size_t)blk * CH + tid] = fmaxf(xr + m1, 0.f);
}

// ---------------------------------------------------------------------------
// K4: x2 = relu(x1 + maxpool5(x)); xfu = relu([x1,x2]@Wfu + bfu);
//     out = x + xfu, stored TRANSPOSED into d_out; accumulate BN sums.
// 8 locations per block.
__global__ __launch_bounds__(256) void k_fuse(
    const float* __restrict__ x, const float* __restrict__ x1,
    const float* __restrict__ Wfu, const float* __restrict__ bfu,
    float* __restrict__ outp, float* __restrict__ sums) {
  __shared__ float cat[8 * 512];
  const int tid = threadIdx.x;
  const int loc0 = blockIdx.x * 8;
  float xv[8];
#pragma unroll
  for (int t = 0; t < 8; ++t) {
    int loc = loc0 + t;
    int beta = loc & 63, alpha = (loc >> 6) & 63, b = loc >> 12;
    const float* xb = x + (size_t)b * 4096 * CH;
    float m2 = -INFINITY;
    for (int dh = -2; dh <= 2; ++dh) {
      int hh = alpha + dh;
      if ((unsigned)hh >= 64u) continue;
      for (int dw = -2; dw <= 2; ++dw) {
        int ww = beta + dw;
        if ((unsigned)ww >= 64u) continue;
        m2 = fmaxf(m2, xb[(size_t)(hh * 64 + ww) * CH + tid]);
      }
    }
    float x1v = x1[(size_t)loc * CH + tid];
    xv[t] = x[(size_t)loc * CH + tid];
    cat[t * 512 + tid] = x1v;
    cat[t * 512 + 256 + tid] = fmaxf(x1v + m2, 0.f);
  }
  __syncthreads();
  float acc[8] = {0.f, 0.f, 0.f, 0.f, 0.f, 0.f, 0.f, 0.f};
  for (int k = 0; k < 512; ++k) {
    float w = Wfu[k * 256 + tid];
#pragma unroll
    for (int t = 0; t < 8; ++t) acc[t] = fmaf(cat[t * 512 + k], w, acc[t]);
  }
  const float bb = bfu[tid];
  float ps = 0.f, pss = 0.f;
#pragma unroll
  for (int t = 0; t < 8; ++t) {
    int loc = loc0 + t;
    int beta = loc & 63, alpha = (loc >> 6) & 63, b = loc >> 12;
    float o = xv[t] + fmaxf(acc[t] + bb, 0.f);
    // final output layout [B,W,H,C]: position (b, beta, alpha, c)
    outp[((size_t)(b * 64 + beta) * 64 + alpha) * CH + tid] = o;
    ps += o;
    pss += o * o;
  }
  atomicAdd(&sums[tid], ps);
  atomicAdd(&sums[256 + tid], pss);
}

// ---------------------------------------------------------------------------
// K5: per-channel scale/shift from accumulated sums
__global__ void k_bnprep(const float* __restrict__ sums,
                         const float* __restrict__ gamma,
                         const float* __restrict__ beta_,
                         float* __restrict__ sc) {
  int c = threadIdx.x;
  const float inv_n = 1.f / (float)NLOC;
  float mean = sums[c] * inv_n;
  float var = sums[256 + c] * inv_n - mean * mean;
  float scale = gamma[c] * rsqrtf(var + 1e-5f);
  sc[c] = scale;
  sc[256 + c] = beta_[c] - mean * scale;
}

// ---------------------------------------------------------------------------
// K6: in-place normalize d_out (float4 vectorized)
__global__ __launch_bounds__(256) void k_bn(
    float* __restrict__ outp, const float* __restrict__ sc, int n4) {
  __shared__ float s[512];
  const int tid = threadIdx.x;
  for (int i = tid; i < 512; i += 256) s[i] = sc[i];
  __syncthreads();
  for (int i = blockIdx.x * 256 + tid; i < n4; i += gridDim.x * 256) {
    float4 val = ((float4*)outp)[i];
    int c0 = (i & 63) * 4;
    val.x = val.x * s[c0 + 0] + s[256 + c0 + 0];
    val.y = val.y * s[c0 + 1] + s[256 + c0 + 1];
    val.z = val.z * s[c0 + 2] + s[256 + c0 + 2];
    val.w = val.w * s[c0 + 3] + s[256 + c0 + 3];
    ((float4*)outp)[i] = val;
  }
}

// ---------------------------------------------------------------------------
extern "C" void kernel_launch(void* const* d_in, const int* in_sizes, int n_in,
                              void* d_out, int out_size, void* d_ws, size_t ws_size,
                              hipStream_t stream) {
  const float* x    = (const float*)d_in[0];
  const float* Wv   = (const float*)d_in[1];
  const float* bv   = (const float*)d_in[2];
  const float* Wa   = (const float*)d_in[3];
  const float* ba   = (const float*)d_in[4];
  const float* Wfu  = (const float*)d_in[5];
  const float* bfu  = (const float*)d_in[6];
  const float* gamma = (const float*)d_in[7];
  const float* beta_ = (const float*)d_in[8];
  float* out = (float*)d_out;

  float* ws = (float*)d_ws;
  float* v    = ws;                     // 8,388,608 floats
  float* A    = v + (size_t)NLOC * CH;  // 2,654,208 floats
  float* x1   = A + (size_t)NLOC * 81;  // 8,388,608 floats
  float* sums = x1 + (size_t)NLOC * CH; // 512 floats
  float* sc   = sums + 512;             // 512 floats

  hipMemsetAsync(sums, 0, 512 * sizeof(float), stream);

  k_gemm_v<<<NLOC / 8, 256, 0, stream>>>(x, Wv, bv, v);
  k_gemm_a<<<NLOC / 16, 256, 0, stream>>>(x, Wa, ba, A);
  k_attn<<<NLOC, 256, 0, stream>>>(A, v, x, x1);
  k_fuse<<<NLOC / 8, 256, 0, stream>>>(x, x1, Wfu, bfu, out, sums);
  k_bnprep<<<1, 256, 0, stream>>>(sums, gamma, beta_, sc);
  k_bn<<<2048, 256, 0, stream>>>(out, sc, NLOC * CH / 4);
}

// Round 2
// 182.442 us; speedup vs baseline: 3.4171x; 3.4171x over previous
//
#include <hip/hip_runtime.h>
#include <math.h>

#define NLOC 32768
#define CH 256

typedef __attribute__((ext_vector_type(8))) short short8;
typedef __attribute__((ext_vector_type(4))) float floatx4;

__device__ inline unsigned short f2bf(float x) {
  union { float f; unsigned u; } c; c.f = x;
  unsigned r = c.u + 0x7FFFu + ((c.u >> 16) & 1u);
  return (unsigned short)(r >> 16);
}

// ---------------------------------------------------------------------------
// P0: pack Wv/Wfu/Wa(->96 cols, zero-pad) to bf16 MFMA B-fragment order:
//     frag f: lane l holds B[k = ks*32+(l>>4)*8+j][c = nf*16+(l&15)], j=0..7
//     layout: wp[f*512 + l*8 + j]
__global__ __launch_bounds__(64) void k_pack_w(
    const float* __restrict__ Wv, const float* __restrict__ Wa,
    const float* __restrict__ Wfu, unsigned short* __restrict__ wp) {
  int fid = blockIdx.x;
  int l = threadIdx.x;
  const float* W; int ldn, nvalid, nf, ks;
  if (fid < 128)      { W = Wv;  ldn = 256; nvalid = 256; nf = fid >> 3; ks = fid & 7; }
  else if (fid < 384) { int f = fid - 128; W = Wfu; ldn = 256; nvalid = 256; nf = f >> 4; ks = f & 15; }
  else                { int f = fid - 384; W = Wa;  ldn = 81;  nvalid = 81;  nf = f >> 3; ks = f & 7; }
  unsigned short* dst = wp + (size_t)fid * 512;
  int c = nf * 16 + (l & 15);
  int k0 = ks * 32 + (l >> 4) * 8;
  unsigned short u[8];
#pragma unroll
  for (int j = 0; j < 8; ++j)
    u[j] = (c < nvalid) ? f2bf(W[(size_t)(k0 + j) * ldn + c]) : (unsigned short)0;
  uint4 pk;
  pk.x = u[0] | ((unsigned)u[1] << 16);
  pk.y = u[2] | ((unsigned)u[3] << 16);
  pk.z = u[4] | ((unsigned)u[5] << 16);
  pk.w = u[6] | ((unsigned)u[7] << 16);
  *(uint4*)(dst + l * 8) = pk;
}

// A-fragment from f32 row-major x: lane reads 8 consecutive f32, cvt to bf16
__device__ inline short8 load_afrag_f32(const float* rowptr) {
  float4 f0 = *(const float4*)(rowptr);
  float4 f1 = *(const float4*)(rowptr + 4);
  union { short8 s; unsigned short u[8]; } r;
  r.u[0]=f2bf(f0.x); r.u[1]=f2bf(f0.y); r.u[2]=f2bf(f0.z); r.u[3]=f2bf(f0.w);
  r.u[4]=f2bf(f1.x); r.u[5]=f2bf(f1.y); r.u[6]=f2bf(f1.z); r.u[7]=f2bf(f1.w);
  return r.s;
}

// ---------------------------------------------------------------------------
// P2a: v = bf16(x) @ Wv + bv  -> v stored bf16 row-major [loc][256]
// wave = (mtile, nhalf): 16 rows x 128 cols, K=256. No LDS.
__global__ __launch_bounds__(256) void k_gemm_v(
    const float* __restrict__ x, const unsigned short* __restrict__ wvp,
    const float* __restrict__ bv, unsigned short* __restrict__ v) {
  int tid = threadIdx.x, lane = tid & 63, w = tid >> 6;
  int mtile = blockIdx.x * 2 + (w >> 1);
  int nhalf = w & 1;
  int r0 = mtile * 16;
  floatx4 acc[8];
#pragma unroll
  for (int i = 0; i < 8; ++i) acc[i] = (floatx4)(0.f);
  int arow = r0 + (lane & 15);
  const float* xbase = x + (size_t)arow * CH + (lane >> 4) * 8;
  for (int ks = 0; ks < 8; ++ks) {
    short8 af = load_afrag_f32(xbase + ks * 32);
    const unsigned short* bp = wvp + ((size_t)(nhalf * 8) * 8 + ks) * 512 + lane * 8;
#pragma unroll
    for (int nf = 0; nf < 8; ++nf) {
      short8 bfr = *(const short8*)(bp + (size_t)nf * 8 * 512);
      acc[nf] = __builtin_amdgcn_mfma_f32_16x16x32_bf16(af, bfr, acc[nf], 0, 0, 0);
    }
  }
  int crow = r0 + (lane >> 4) * 4;
#pragma unroll
  for (int nf = 0; nf < 8; ++nf) {
    int c = nhalf * 128 + nf * 16 + (lane & 15);
    float bb = bv[c];
#pragma unroll
    for (int i = 0; i < 4; ++i)
      v[(size_t)(crow + i) * CH + c] = f2bf(acc[nf][i] + bb);
  }
}

// ---------------------------------------------------------------------------
// P2b: logits = bf16(x) @ Wa + ba (96 cols, 81 valid) -> softmax9 -> A f32 [loc][81]
__global__ __launch_bounds__(256) void k_gemm_a(
    const float* __restrict__ x, const unsigned short* __restrict__ wap,
    const float* __restrict__ ba, float* __restrict__ A) {
  __shared__ float lg[64][96];
  int tid = threadIdx.x, lane = tid & 63, w = tid >> 6;
  int mtile = blockIdx.x * 4 + w;
  int r0 = mtile * 16;
  floatx4 acc[6];
#pragma unroll
  for (int i = 0; i < 6; ++i) acc[i] = (floatx4)(0.f);
  int arow = r0 + (lane & 15);
  const float* xbase = x + (size_t)arow * CH + (lane >> 4) * 8;
  for (int ks = 0; ks < 8; ++ks) {
    short8 af = load_afrag_f32(xbase + ks * 32);
#pragma unroll
    for (int nf = 0; nf < 6; ++nf) {
      short8 bfr = *(const short8*)(wap + ((size_t)(nf * 8) + ks) * 512 + lane * 8);
      acc[nf] = __builtin_amdgcn_mfma_f32_16x16x32_bf16(af, bfr, acc[nf], 0, 0, 0);
    }
  }
  int lrow = w * 16 + (lane >> 4) * 4;
#pragma unroll
  for (int nf = 0; nf < 6; ++nf) {
    int c = nf * 16 + (lane & 15);
    float bb = (c < 81) ? ba[c] : 0.f;
#pragma unroll
    for (int i = 0; i < 4; ++i)
      lg[lrow + i][c] = acc[nf][i] + bb;
  }
  __syncthreads();
  int loc0 = blockIdx.x * 64;
  for (int it = 0; it < 3; ++it) {
    int idx = tid + it * 256;
    if (idx < 576) {
      int row = idx / 9, g = idx % 9;
      float vals[9];
#pragma unroll
      for (int q = 0; q < 9; ++q) vals[q] = lg[row][g * 9 + q];
      float m = vals[0];
#pragma unroll
      for (int q = 1; q < 9; ++q) m = fmaxf(m, vals[q]);
      float s = 0.f;
#pragma unroll
      for (int q = 0; q < 9; ++q) { vals[q] = __expf(vals[q] - m); s += vals[q]; }
      float inv = 1.f / s;
      float* o = A + (size_t)(loc0 + row) * 81 + g * 9;
#pragma unroll
      for (int q = 0; q < 9; ++q) o[q] = vals[q] * inv;
    }
  }
}

// ---------------------------------------------------------------------------
// P3: attention gather (5x5 of v with folded weights) + maxpool3 + maxpool5
//     -> cat = [x1 | x2] written bf16 in MFMA A-fragment order (catpack)
// block = 16 locations (same b,alpha; beta0..beta0+15)
__global__ __launch_bounds__(256) void k_attn(
    const float* __restrict__ A, const unsigned short* __restrict__ v,
    const float* __restrict__ x, unsigned short* __restrict__ catp) {
  __shared__ float a_s[16][81];
  __shared__ float w5_s[16][26];
  int tid = threadIdx.x;
  int loc0 = blockIdx.x * 16;
  int b = loc0 >> 12, alpha = (loc0 >> 6) & 63, beta0 = loc0 & 63;
  for (int idx = tid; idx < 16 * 81; idx += 256) {
    int li = idx / 81, t = idx % 81;
    int ij = t / 9, i = ij / 3, j = ij % 3;
    int lh = (beta0 + li) + 1 - i;
    int lw = alpha + 1 - j;
    float val = 0.f;
    if ((unsigned)lh < 64u && (unsigned)lw < 64u)
      val = A[(size_t)(b * 4096 + lh * 64 + lw) * 81 + t];
    a_s[li][t] = val;
  }
  __syncthreads();
  for (int idx = tid; idx < 16 * 25; idx += 256) {
    int li = idx / 25, o = idx % 25;
    int dh = o / 5 - 2, dw = o % 5 - 2;
    float s = 0.f;
    int jlo = dh < 0 ? -dh : 0, jhi = dh > 0 ? 2 - dh : 2;
    int ilo = dw < 0 ? -dw : 0, ihi = dw > 0 ? 2 - dw : 2;
    for (int j = jlo; j <= jhi; ++j)
      for (int i = ilo; i <= ihi; ++i)
        s += a_s[li][(i * 3 + j) * 9 + ((i + dw) * 3 + (j + dh))];
    w5_s[li][o] = s;
  }
  __syncthreads();
  int li = tid >> 4, c0 = (tid & 15) * 16;
  int beta = beta0 + li;
  float acc[16];
#pragma unroll
  for (int q = 0; q < 16; ++q) acc[q] = 0.f;
  const unsigned short* vb = v + (size_t)b * 4096 * CH;
#pragma unroll
  for (int dh = -2; dh <= 2; ++dh) {
    int hv = alpha + dh;
    if ((unsigned)hv >= 64u) continue;
#pragma unroll
    for (int dw = -2; dw <= 2; ++dw) {
      int wv = beta + dw;
      if ((unsigned)wv >= 64u) continue;
      float wgt = w5_s[li][(dh + 2) * 5 + (dw + 2)];
      const uint4* vp = (const uint4*)(vb + (size_t)(hv * 64 + wv) * CH + c0);
      uint4 p0 = vp[0], p1 = vp[1];
      unsigned pk[8] = {p0.x, p0.y, p0.z, p0.w, p1.x, p1.y, p1.z, p1.w};
#pragma unroll
      for (int d = 0; d < 8; ++d) {
        union { unsigned u; float f; } lo, hi;
        lo.u = pk[d] << 16; hi.u = pk[d] & 0xFFFF0000u;
        acc[d * 2]     = fmaf(wgt, lo.f, acc[d * 2]);
        acc[d * 2 + 1] = fmaf(wgt, hi.f, acc[d * 2 + 1]);
      }
    }
  }
  float m1[16], m2[16];
#pragma unroll
  for (int q = 0; q < 16; ++q) { m1[q] = -INFINITY; m2[q] = -INFINITY; }
  const float* xb = x + (size_t)b * 4096 * CH;
#pragma unroll
  for (int dh = -2; dh <= 2; ++dh) {
    int hh = alpha + dh;
    if ((unsigned)hh >= 64u) continue;
#pragma unroll
    for (int dw = -2; dw <= 2; ++dw) {
      int ww = beta + dw;
      if ((unsigned)ww >= 64u) continue;
      const float4* xp = (const float4*)(xb + (size_t)(hh * 64 + ww) * CH + c0);
      const bool inner = (dh >= -1 && dh <= 1 && dw >= -1 && dw <= 1);
#pragma unroll
      for (int d = 0; d < 4; ++d) {
        float4 f = xp[d];
        int q = d * 4;
        m2[q + 0] = fmaxf(m2[q + 0], f.x);
        m2[q + 1] = fmaxf(m2[q + 1], f.y);
        m2[q + 2] = fmaxf(m2[q + 2], f.z);
        m2[q + 3] = fmaxf(m2[q + 3], f.w);
        if (inner) {
          m1[q + 0] = fmaxf(m1[q + 0], f.x);
          m1[q + 1] = fmaxf(m1[q + 1], f.y);
          m1[q + 2] = fmaxf(m1[q + 2], f.z);
          m1[q + 3] = fmaxf(m1[q + 3], f.w);
        }
      }
    }
  }
  int loc = loc0 + li;
  int mt = loc >> 4;  // == blockIdx.x
  unsigned short u1[16], u2[16];
#pragma unroll
  for (int q = 0; q < 16; ++q) {
    float x1v = fmaxf(fmaxf(acc[q], 0.f) + m1[q], 0.f);
    float x2v = fmaxf(x1v + m2[q], 0.f);
    u1[q] = f2bf(x1v);
    u2[q] = f2bf(x2v);
  }
  // store catpack: element (loc, k): ks=k>>5, lane=((k>>3)&3)*16+(loc&15), j=k&7
#pragma unroll
  for (int half = 0; half < 2; ++half) {
    const unsigned short* uu = half ? u2 : u1;
    int kb = half * 256 + c0;
#pragma unroll
    for (int g = 0; g < 2; ++g) {
      int k = kb + g * 8;
      int ks = k >> 5, lgp = (k >> 3) & 3;
      uint4 pk;
      pk.x = uu[g*8+0] | ((unsigned)uu[g*8+1] << 16);
      pk.y = uu[g*8+2] | ((unsigned)uu[g*8+3] << 16);
      pk.z = uu[g*8+4] | ((unsigned)uu[g*8+5] << 16);
      pk.w = uu[g*8+6] | ((unsigned)uu[g*8+7] << 16);
      *(uint4*)(catp + (((size_t)mt * 16 + ks) * 64 + lgp * 16 + li) * 8) = pk;
    }
  }
}

// ---------------------------------------------------------------------------
// P4: xfu = relu(cat @ Wfu + bfu); out = x + xfu stored transposed; BN sums.
// wave = (mtile, nhalf), K=512, A-frags direct coalesced loads from catpack.
__global__ __launch_bounds__(256) void k_fuse(
    const float* __restrict__ x, const unsigned short* __restrict__ catp,
    const unsigned short* __restrict__ wfp, const float* __restrict__ bfu,
    float* __restrict__ outp, float* __restrict__ sums) {
  __shared__ float bsum[512];
  int tid = threadIdx.x, lane = tid & 63, w = tid >> 6;
  for (int i = tid; i < 512; i += 256) bsum[i] = 0.f;
  __syncthreads();
  int gw = blockIdx.x * 4 + w;
  int mtile = gw >> 1, nhalf = gw & 1;
  int r0 = mtile * 16;
  floatx4 acc[8];
#pragma unroll
  for (int i = 0; i < 8; ++i) acc[i] = (floatx4)(0.f);
  const unsigned short* ab = catp + (size_t)mtile * 16 * 512 + lane * 8;
  for (int ks = 0; ks < 16; ++ks) {
    short8 af = *(const short8*)(ab + (size_t)ks * 512);
    const unsigned short* bp = wfp + ((size_t)(nhalf * 8) * 16 + ks) * 512 + lane * 8;
#pragma unroll
    for (int nf = 0; nf < 8; ++nf) {
      short8 bfr = *(const short8*)(bp + (size_t)nf * 16 * 512);
      acc[nf] = __builtin_amdgcn_mfma_f32_16x16x32_bf16(af, bfr, acc[nf], 0, 0, 0);
    }
  }
  int crow = r0 + (lane >> 4) * 4;
#pragma unroll
  for (int nf = 0; nf < 8; ++nf) {
    int c = nhalf * 128 + nf * 16 + (lane & 15);
    float bb = bfu[c];
    float s = 0.f, ss = 0.f;
#pragma unroll
    for (int i = 0; i < 4; ++i) {
      int r = crow + i;
      float xv = x[(size_t)r * CH + c];
      float o = xv + fmaxf(acc[nf][i] + bb, 0.f);
      int b_ = r >> 12, al = (r >> 6) & 63, be = r & 63;
      outp[((size_t)(b_ * 64 + be) * 64 + al) * CH + c] = o;
      s += o; ss += o * o;
    }
    s += __shfl_xor(s, 16);  s += __shfl_xor(s, 32);
    ss += __shfl_xor(ss, 16); ss += __shfl_xor(ss, 32);
    if (lane < 16) {
      atomicAdd(&bsum[c], s);
      atomicAdd(&bsum[256 + c], ss);
    }
  }
  __syncthreads();
  for (int i = tid; i < 512; i += 256) atomicAdd(&sums[i], bsum[i]);
}

// ---------------------------------------------------------------------------
__global__ void k_bnprep(const float* __restrict__ sums,
                         const float* __restrict__ gamma,
                         const float* __restrict__ beta_,
                         float* __restrict__ sc) {
  int c = threadIdx.x;
  const float inv_n = 1.f / (float)NLOC;
  float mean = sums[c] * inv_n;
  float var = sums[256 + c] * inv_n - mean * mean;
  float scale = gamma[c] * rsqrtf(var + 1e-5f);
  sc[c] = scale;
  sc[256 + c] = beta_[c] - mean * scale;
}

__global__ __launch_bounds__(256) void k_bn(
    float* __restrict__ outp, const float* __restrict__ sc, int n4) {
  __shared__ float s[512];
  const int tid = threadIdx.x;
  for (int i = tid; i < 512; i += 256) s[i] = sc[i];
  __syncthreads();
  for (int i = blockIdx.x * 256 + tid; i < n4; i += gridDim.x * 256) {
    float4 val = ((float4*)outp)[i];
    int c0 = (i & 63) * 4;
    val.x = val.x * s[c0 + 0] + s[256 + c0 + 0];
    val.y = val.y * s[c0 + 1] + s[256 + c0 + 1];
    val.z = val.z * s[c0 + 2] + s[256 + c0 + 2];
    val.w = val.w * s[c0 + 3] + s[256 + c0 + 3];
    ((float4*)outp)[i] = val;
  }
}

// ---------------------------------------------------------------------------
extern "C" void kernel_launch(void* const* d_in, const int* in_sizes, int n_in,
                              void* d_out, int out_size, void* d_ws, size_t ws_size,
                              hipStream_t stream) {
  const float* x     = (const float*)d_in[0];
  const float* Wv    = (const float*)d_in[1];
  const float* bv    = (const float*)d_in[2];
  const float* Wa    = (const float*)d_in[3];
  const float* ba    = (const float*)d_in[4];
  const float* Wfu   = (const float*)d_in[5];
  const float* bfu   = (const float*)d_in[6];
  const float* gamma = (const float*)d_in[7];
  const float* beta_ = (const float*)d_in[8];
  float* out = (float*)d_out;

  float* sums = (float*)d_ws;                               // 512 f32
  float* sc   = sums + 512;                                 // 512 f32
  unsigned short* wp   = (unsigned short*)(sc + 512);       // 432*512 bf16
  unsigned short* wvp  = wp;                                // frags 0..127
  unsigned short* wfp  = wp + (size_t)128 * 512;            // frags 128..383
  unsigned short* wap  = wp + (size_t)384 * 512;            // frags 384..431
  unsigned short* vbuf = wp + (size_t)432 * 512;            // NLOC*256 bf16
  float* Abuf = (float*)(vbuf + (size_t)NLOC * CH);         // NLOC*81 f32
  unsigned short* catp = (unsigned short*)(Abuf + (size_t)NLOC * 81); // NLOC*512 bf16

  hipMemsetAsync(sums, 0, 512 * sizeof(float), stream);

  k_pack_w<<<432, 64, 0, stream>>>(Wv, Wa, Wfu, wp);
  k_gemm_v<<<1024, 256, 0, stream>>>(x, wvp, bv, vbuf);
  k_gemm_a<<<512, 256, 0, stream>>>(x, wap, ba, Abuf);
  k_attn<<<2048, 256, 0, stream>>>(Abuf, vbuf, x, catp);
  k_fuse<<<1024, 256, 0, stream>>>(x, catp, wfp, bfu, out, sums);
  k_bnprep<<<1, 256, 0, stream>>>(sums, gamma, beta_, sc);
  k_bn<<<2048, 256, 0, stream>>>(out, sc, NLOC * CH / 4);
}